// Round 12
// baseline (593.368 us; speedup 1.0000x reference)
//
#include <hip/hip_runtime.h>
#include <cstdint>

using u8 = unsigned char;
using u64 = unsigned long long;

typedef _Float16 f16x8 __attribute__((ext_vector_type(8)));
typedef float f32x4 __attribute__((ext_vector_type(4)));
typedef unsigned char u8x16 __attribute__((ext_vector_type(16)));

__device__ __forceinline__ void gload16(const void* g, void* l) {
  __builtin_amdgcn_global_load_lds((const __attribute__((address_space(1))) void*)g,
                                   (__attribute__((address_space(3))) void*)l, 16, 0, 0);
}

#define VMCNT(N) asm volatile("s_waitcnt vmcnt(" #N ")" ::: "memory")

// ---- fp32 [C][N] slice -> f16 hi/lo planes [N][C] (+ optional partial sum-sq)
__device__ __forceinline__ void split_body(const float* __restrict__ in,
                                           _Float16* __restrict__ hi,
                                           _Float16* __restrict__ lo,
                                           float* __restrict__ hnp,
                                           int C, int N, int NC,
                                           int cblk, int nblk, int b, bool with_hn) {
  const int n = nblk * 256 + (int)threadIdx.x;
  const int c0 = cblk * 32;
  const float* inB = in + (size_t)b * C * N;
  f16x8 hv[4], lv[4];
  float ss = 0.f;
#pragma unroll
  for (int g = 0; g < 4; ++g)
#pragma unroll
    for (int e = 0; e < 8; ++e) {
      float x = inB[(size_t)(c0 + g * 8 + e) * N + n];
      _Float16 h = (_Float16)x;
      float r = (x - (float)h) * 4096.f;
      hv[g][e] = h;
      lv[g][e] = (_Float16)r;
      ss = fmaf(x, x, ss);
    }
  _Float16* oh = hi + ((size_t)b * N + n) * C + c0;
  _Float16* ol = lo + ((size_t)b * N + n) * C + c0;
#pragma unroll
  for (int g = 0; g < 4; ++g) {
    *(f16x8*)(oh + g * 8) = hv[g];
    *(f16x8*)(ol + g * 8) = lv[g];
  }
  if (with_hn) hnp[((size_t)b * NC + cblk) * N + n] = ss;
}

// one launch for all 4 tensors: flat grid 2048*2 (L1) + 1024*2 (L2) = 6144
__global__ __launch_bounds__(256) void prep_all(
    const float* __restrict__ s1, const float* __restrict__ t1,
    const float* __restrict__ s2, const float* __restrict__ t2,
    _Float16* __restrict__ h1s, _Float16* __restrict__ l1s,
    _Float16* __restrict__ h1t, _Float16* __restrict__ l1t,
    _Float16* __restrict__ h2s, _Float16* __restrict__ l2s,
    _Float16* __restrict__ h2t, _Float16* __restrict__ l2t,
    float* __restrict__ hnp1, float* __restrict__ hnp2) {
  const int f = (int)blockIdx.x;
  if (f < 4096) {  // L1: C=1024, N=4096; 32 c-blocks x 16 n-blocks x 4 b
    const bool isT = f >= 2048;
    const int local = f & 2047;
    const int cblk = local & 31;
    const int r = local >> 5;
    const int nblk = r & 15, b = r >> 4;
    split_body(isT ? t1 : s1, isT ? h1t : h1s, isT ? l1t : l1s, hnp1,
               1024, 4096, 32, cblk, nblk, b, isT);
  } else {         // L2: C=2048, N=1024; 64 c-blocks x 4 n-blocks x 4 b
    const int l0 = f - 4096;
    const bool isT = l0 >= 1024;
    const int local = l0 & 1023;
    const int cblk = local & 63;
    const int r = local >> 6;
    const int nblk = r & 3, b = r >> 2;
    split_body(isT ? t2 : s2, isT ? h2t : h2s, isT ? l2t : l2s, hnp2,
               2048, 1024, 64, cblk, nblk, b, isT);
  }
}

// ---- hn[b][n] = 0.5 * sum over chunks, both levels in one launch ------------
__global__ __launch_bounds__(256) void hn_all(const float* __restrict__ hnp1,
                                              const float* __restrict__ hnp2,
                                              float* __restrict__ hn1,
                                              float* __restrict__ hn2) {
  const int x = (int)blockIdx.x, b = (int)blockIdx.y;
  if (x < 16) {
    const int n = x * 256 + (int)threadIdx.x;
    float a = 0.f;
    for (int cc = 0; cc < 32; ++cc) a += hnp1[((size_t)b * 32 + cc) * 4096 + n];
    hn1[(size_t)b * 4096 + n] = 0.5f * a;
  } else {
    const int n = (x - 16) * 256 + (int)threadIdx.x;
    float a = 0.f;
    for (int cc = 0; cc < 64; ++cc) a += hnp2[((size_t)b * 64 + cc) * 1024 + n];
    hn2[(size_t)b * 1024 + n] = 0.5f * a;
  }
}

// ---- f16-hi filter GEMM, validated phase schedule; L1+L2 in ONE launch ------
// Epilogue: per-(row, 256-col tile) min (u16) + dense u8 deltas clamped at 255
// (a clamped delta can never re-qualify: tilemin+255 > gmin+64 always).
#define MFMA_BLOCK(GI)                                                         \
  __builtin_amdgcn_s_barrier();                                                \
  asm volatile("s_waitcnt lgkmcnt(0)" ::: "memory");                           \
  __builtin_amdgcn_sched_barrier(0);                                           \
  __builtin_amdgcn_s_setprio(1);                                               \
  _Pragma("unroll") for (int i2 = 0; i2 < 4; ++i2)                             \
      _Pragma("unroll") for (int j = 0; j < NJ; ++j) acc[(GI)*4 + i2][j] =     \
      __builtin_amdgcn_mfma_f32_16x16x32_f16(av[i2], bv[j],                    \
                                             acc[(GI)*4 + i2][j], 0, 0, 0);    \
  __builtin_amdgcn_s_setprio(0);                                               \
  asm volatile("" ::: "memory");                                               \
  __builtin_amdgcn_s_barrier();

constexpr unsigned DELTA_Q = 64;  // 1.0 in score units (x64 quant)

// body: 256x256 tile, 512 threads (2x4 waves), MI=8, NJ=4
__device__ __forceinline__ void filter_body(
    const u8* __restrict__ Ahi, const u8* __restrict__ Bhi,
    const float* __restrict__ hn, u8* __restrict__ sc,
    unsigned short* __restrict__ g_tmin, int nTiles,
    int M, int N, int NT, int mbase, int nbase, int b, u8* smem) {
  constexpr int MI = 8, NJ = 4;
  constexpr int BM = 256;
  constexpr int CHUNK_A = BM * 64;   // 16 KB
  constexpr int CHUNK = 2 * CHUNK_A; // 32 KB
  constexpr int NTH = 512;

  const int tid = threadIdx.x;
  const int lane = tid & 63;
  const int wid = tid >> 6;
  const int wrow = wid >> 2;   // /4
  const int wcol = wid & 3;    // %4
  const int lr = lane & 15, kh = lane >> 4;
  const size_t rstride = (size_t)NT * 128;

  const int r0 = (tid >> 6) * 16 + ((tid & 63) >> 2);
  const int sA = ((lane & 3) ^ (r0 >> 1)) & 3;
  const u8* aP0 = Ahi + ((size_t)b * M + mbase + r0) * rstride + sA * 16;
  const u8* aP1 = aP0 + (size_t)(NTH / 4) * rstride;
  const u8* bP0 = Bhi + ((size_t)b * N + nbase + r0) * rstride + sA * 16;
  const u8* bP1 = bP0 + (size_t)(NTH / 4) * rstride;

  auto STAGE = [&](int X, int h) {
    const size_t ko = (size_t)X * 128 + h * 64;
    u8* cb = smem + ((X & 1) * 2 + h) * CHUNK;
    gload16(aP0 + ko, cb + tid * 16);
    gload16(aP1 + ko, cb + NTH * 16 + tid * 16);
    gload16(bP0 + ko, cb + CHUNK_A + tid * 16);
    gload16(bP1 + ko, cb + CHUNK_A + NTH * 16 + tid * 16);
  };

  int a_off[MI], b_off[NJ];
#pragma unroll
  for (int i = 0; i < MI; ++i) {
    const int row = wrow * (MI * 16) + i * 16 + lr;
    a_off[i] = row * 64 + (((kh ^ (row >> 1)) & 3) << 4);
  }
#pragma unroll
  for (int j = 0; j < NJ; ++j) {
    const int row = wcol * (NJ * 16) + j * 16 + lr;
    b_off[j] = CHUNK_A + row * 64 + (((kh ^ (row >> 1)) & 3) << 4);
  }

  f32x4 acc[MI][NJ];
#pragma unroll
  for (int i = 0; i < MI; ++i)
#pragma unroll
    for (int j = 0; j < NJ; ++j) acc[i][j] = f32x4{0.f, 0.f, 0.f, 0.f};

  STAGE(0, 0);
  STAGE(0, 1);
  STAGE(1, 0);
  VMCNT(8);
  __builtin_amdgcn_s_barrier();

  for (int X = 0; X < NT; ++X) {
    const u8* cb0 = smem + ((X & 1) * 2) * CHUNK;
    const u8* cb1 = cb0 + CHUNK;
    f16x8 av[4], bv[NJ];

#pragma unroll
    for (int j = 0; j < NJ; ++j) bv[j] = *(const f16x8*)(cb0 + b_off[j]);
#pragma unroll
    for (int i2 = 0; i2 < 4; ++i2) av[i2] = *(const f16x8*)(cb0 + a_off[i2]);
    if (X + 1 < NT) STAGE(X + 1, 1);
    if (X + 1 < NT) { VMCNT(8); } else { VMCNT(0); }
    MFMA_BLOCK(0)

#pragma unroll
    for (int i2 = 0; i2 < 4; ++i2) av[i2] = *(const f16x8*)(cb0 + a_off[4 + i2]);
    MFMA_BLOCK(1)

#pragma unroll
    for (int j = 0; j < NJ; ++j) bv[j] = *(const f16x8*)(cb1 + b_off[j]);
#pragma unroll
    for (int i2 = 0; i2 < 4; ++i2) av[i2] = *(const f16x8*)(cb1 + a_off[i2]);
    if (X + 2 < NT) STAGE(X + 2, 0);
    if (X + 1 < NT) {
      if (X + 2 < NT) { VMCNT(8); } else { VMCNT(4); }
    }
    MFMA_BLOCK(0)

#pragma unroll
    for (int i2 = 0; i2 < 4; ++i2) av[i2] = *(const f16x8*)(cb1 + a_off[4 + i2]);
    MFMA_BLOCK(1)
  }

  // ---- epilogue --------------------------------------------------------------
  const float* hnB = hn + (size_t)b * N;
  const int tileIdx = nbase >> 8;
  float hnv[NJ];
  int ncol[NJ];
#pragma unroll
  for (int j = 0; j < NJ; ++j) {
    ncol[j] = nbase + wcol * (NJ * 16) + j * 16 + lr;
    hnv[j] = hnB[ncol[j]];
  }

  auto quant = [&](int i, int j, int r) -> unsigned {
    float s = hnv[j] - acc[i][j][r];
    int qi = (int)(s * 64.0f);
    return (unsigned)(qi < 0 ? 0 : (qi > 65535 ? 65535 : qi));
  };

  unsigned* lmin = (unsigned*)smem;   // [256][4]
  unsigned* tminL = lmin + 256 * 4;   // [256]

  // pass 1: per-row tile-min (16 lr-lanes shfl, then cross-wcol in LDS)
#pragma unroll
  for (int i = 0; i < MI; ++i)
#pragma unroll
    for (int r = 0; r < 4; ++r) {
      unsigned rq = 0xFFFFFFFFu;
#pragma unroll
      for (int j = 0; j < NJ; ++j) {
        unsigned q = quant(i, j, r);
        rq = q < rq ? q : rq;
      }
#pragma unroll
      for (int off = 1; off <= 8; off <<= 1) {
        unsigned o = (unsigned)__shfl_xor((int)rq, off);
        rq = o < rq ? o : rq;
      }
      if (lr == 0) lmin[(wrow * 128 + i * 16 + kh * 4 + r) * 4 + wcol] = rq;
    }
  __syncthreads();
  for (int m = tid; m < 256; m += NTH) {
    unsigned t = lmin[m * 4];
#pragma unroll
    for (int w = 1; w < 4; ++w) {
      unsigned o = lmin[m * 4 + w];
      t = o < t ? o : t;
    }
    tminL[m] = t;
    g_tmin[((size_t)b * M + mbase + m) * nTiles + tileIdx] = (unsigned short)t;
  }
  __syncthreads();
  // pass 2: u8 delta store
  u8* scB = sc + (size_t)b * M * N;
#pragma unroll
  for (int i = 0; i < MI; ++i)
#pragma unroll
    for (int r = 0; r < 4; ++r) {
      const int ml = wrow * 128 + i * 16 + kh * 4 + r;
      const unsigned tm = tminL[ml];
      u8* srow = scB + (size_t)(mbase + ml) * N;
#pragma unroll
      for (int j = 0; j < NJ; ++j) {
        unsigned d = quant(i, j, r) - tm;
        d = d > 255u ? 255u : d;
        srow[ncol[j]] = (u8)d;
      }
    }
}

// merged launch: blocks [0,64) = L2 (M=N=1024, NT=32), [64,1088) = L1
__global__ __launch_bounds__(512, 2) void nn_filter_all(
    const u8* __restrict__ A1, const u8* __restrict__ B1,
    const float* __restrict__ hn1, u8* __restrict__ sc1,
    unsigned short* __restrict__ tmin1,
    const u8* __restrict__ A2, const u8* __restrict__ B2,
    const float* __restrict__ hn2, u8* __restrict__ sc2,
    unsigned short* __restrict__ tmin2) {
  __shared__ u8 smem[4 * 32768];  // 128 KB
  const int bid = (int)blockIdx.x;
  if (bid < 64) {
    const int sbid = (bid & 7) * 8 + (bid >> 3);
    const int b = sbid >> 4;
    const int rr = sbid & 15;
    const int n1 = rr & 3;
    const int mb = rr >> 2;
    filter_body(A2, B2, hn2, sc2, tmin2, 4, 1024, 1024, 32, mb * 256, n1 * 256, b, smem);
  } else {
    const int l = bid - 64;
    const int sbid = (l & 7) * 128 + (l >> 3);
    const int perB = 256;  // 16 x 16
    const int b = sbid / perB;
    const int rr = sbid - b * perB;
    const int n1 = rr & 3;
    const int t2 = rr >> 2;
    const int mb = t2 & 15;
    const int n2 = t2 >> 4;
    filter_body(A1, B1, hn1, sc1, tmin1, 16, 4096, 4096, 16, mb * 256, (n2 * 4 + n1) * 256, b, smem);
  }
}

// ---- select: gmin from tilemins, u8 scan, exact fp32 rescore ----------------
template <int K, int NTILES>
__device__ __forceinline__ void select_body(
    const u8* __restrict__ q8, const unsigned short* __restrict__ g_tmin,
    const _Float16* __restrict__ hiA, const _Float16* __restrict__ loA,
    const _Float16* __restrict__ hiB, const _Float16* __restrict__ loB,
    const float* __restrict__ hn, unsigned* __restrict__ idx,
    int M, int N, int rowblk, int b) {
  const int w = threadIdx.x >> 6, lane = threadIdx.x & 63;
  const int row = rowblk * 4 + w;
  const u8* q = q8 + ((size_t)b * M + row) * N;
  const unsigned short* tmr = g_tmin + ((size_t)b * M + row) * NTILES;

  unsigned tm = 0xFFFFu;
  if (lane < NTILES) tm = tmr[lane];
#pragma unroll
  for (int off = 32; off >= 1; off >>= 1) {
    unsigned o = (unsigned)__shfl_xor((int)tm, off);
    tm = o < tm ? o : tm;
  }
  const int thr = (int)tm + (int)DELTA_Q;

  constexpr int PER = K / 64;
  const float inv = 2.44140625e-4f;
  float sv[PER];
  const _Float16* hA = hiA + ((size_t)b * M + row) * K;
  const _Float16* lA = loA + ((size_t)b * M + row) * K;
#pragma unroll
  for (int i = 0; i < PER; ++i)
    sv[i] = fmaf((float)lA[i * 64 + lane], inv, (float)hA[i * 64 + lane]);

  float bestv = 3.4e38f;
  int bestn = 0x7FFFFFFF;
  const float* hnB = hn + (size_t)b * N;
  constexpr int CH = K == 0 ? 1 : 1;  // placeholder to keep template simple
  const int nch = N >> 10;            // chunks of 1024 cols
  for (int ch = 0; ch < nch; ++ch) {
    const int n0 = ch * 1024 + lane * 16;
    const int lim = thr - (int)tmr[n0 >> 8];
    u8x16 v = *(const u8x16*)(q + n0);
    unsigned hit = 0;
#pragma unroll
    for (int e = 0; e < 16; ++e)
      if ((int)v[e] <= lim) hit |= 1u << e;
    u64 lm = __ballot(hit != 0);
    while (lm) {
      int src = __ffsll((long long)lm) - 1;
      lm &= lm - 1;
      unsigned h = (unsigned)__shfl((int)hit, src);
      const int nb = ch * 1024 + src * 16;
      while (h) {
        int e = __ffs((int)h) - 1;
        h &= h - 1;
        int n = nb + e;
        const _Float16* hB = hiB + ((size_t)b * N + n) * K;
        const _Float16* lB = loB + ((size_t)b * N + n) * K;
        float part = 0.f;
#pragma unroll
        for (int i = 0; i < PER; ++i)
          part = fmaf(sv[i], fmaf((float)lB[i * 64 + lane], inv, (float)hB[i * 64 + lane]), part);
#pragma unroll
        for (int off = 32; off >= 1; off >>= 1) part += __shfl_xor(part, off);
        float scf = hnB[n] - part;
        if (scf < bestv || (scf == bestv && n < bestn)) { bestv = scf; bestn = n; }
      }
    }
  }
  if (lane == 0) idx[(size_t)b * M + row] = (unsigned)bestn;
}

__global__ __launch_bounds__(256) void select_all(
    const u8* __restrict__ sc1, const unsigned short* __restrict__ tmin1,
    const _Float16* __restrict__ h1s, const _Float16* __restrict__ l1s,
    const _Float16* __restrict__ h1t, const _Float16* __restrict__ l1t,
    const float* __restrict__ hn1, unsigned* __restrict__ idx1,
    const u8* __restrict__ sc2, const unsigned short* __restrict__ tmin2,
    const _Float16* __restrict__ h2s, const _Float16* __restrict__ l2s,
    const _Float16* __restrict__ h2t, const _Float16* __restrict__ l2t,
    const float* __restrict__ hn2, unsigned* __restrict__ idx2) {
  const int x = (int)blockIdx.x, b = (int)blockIdx.y;
  if (x < 1024)
    select_body<1024, 16>(sc1, tmin1, h1s, l1s, h1t, l1t, hn1, idx1, 4096, 4096, x, b);
  else
    select_body<2048, 4>(sc2, tmin2, h2s, l2s, h2t, l2t, hn2, idx2, 1024, 1024, x - 1024, b);
}

// ---- finalize: c1 = [src1|gather] and upsampled c2, one launch --------------
__global__ __launch_bounds__(256) void finalize(
    const float* __restrict__ src1, const float* __restrict__ tar1,
    const float* __restrict__ src2, const float* __restrict__ tar2,
    const unsigned* __restrict__ idx1, const unsigned* __restrict__ idx2,
    float* __restrict__ out) {
  const int b = blockIdx.y;
  int c = (int)blockIdx.x;
  if (c < 2048) {
    float* orow = out + ((size_t)b * 6144 + c) * 4096;
    if (c < 1024) {
      const float4* s4 = (const float4*)(src1 + ((size_t)b * 1024 + c) * 4096);
      float4* o4 = (float4*)orow;
#pragma unroll
      for (int i = 0; i < 4; ++i) o4[threadIdx.x + i * 256] = s4[threadIdx.x + i * 256];
    } else {
      const float* trow = tar1 + ((size_t)b * 1024 + (c - 1024)) * 4096;
      const unsigned* ib = idx1 + (size_t)b * 4096;
      for (int p = threadIdx.x; p < 4096; p += 256) orow[p] = trow[ib[p]];
    }
    return;
  }
  c -= 2048;  // upsample channel 0..4095
  __shared__ float row[1024];
  if (c < 2048) {
    const float* in = src2 + ((size_t)b * 2048 + c) * 1024;
    for (int p = threadIdx.x; p < 1024; p += 256) row[p] = in[p];
  } else {
    const float* trow = tar2 + ((size_t)b * 2048 + (c - 2048)) * 1024;
    const unsigned* ib = idx2 + (size_t)b * 1024;
    for (int p = threadIdx.x; p < 1024; p += 256) row[p] = trow[ib[p]];
  }
  __syncthreads();
  float* orow = out + ((size_t)b * 6144 + 2048 + c) * 4096;
  for (int q = threadIdx.x; q < 4096; q += 256) {
    int y = q >> 6, x = q & 63;
    int ky = y >> 1, kx = x >> 1;
    int y0, y1, x0, x1;
    float wy0, wy1, wx0, wx1;
    if (y & 1) { y0 = ky; y1 = (ky + 1 < 32) ? ky + 1 : 31; wy0 = 0.75f; wy1 = 0.25f; }
    else       { y0 = (ky > 0) ? ky - 1 : 0; y1 = ky;       wy0 = 0.25f; wy1 = 0.75f; }
    if (x & 1) { x0 = kx; x1 = (kx + 1 < 32) ? kx + 1 : 31; wx0 = 0.75f; wx1 = 0.25f; }
    else       { x0 = (kx > 0) ? kx - 1 : 0; x1 = kx;       wx0 = 0.25f; wx1 = 0.75f; }
    float v = wy0 * (wx0 * row[y0 * 32 + x0] + wx1 * row[y0 * 32 + x1]) +
              wy1 * (wx0 * row[y1 * 32 + x0] + wx1 * row[y1 * 32 + x1]);
    orow[q] = v;
  }
}

// ---------------- launch -----------------------------------------------------
extern "C" void kernel_launch(void* const* d_in, const int* in_sizes, int n_in,
                              void* d_out, int out_size, void* d_ws, size_t ws_size,
                              hipStream_t stream) {
  const float* src1 = (const float*)d_in[0];  // [4,1024,64,64]
  const float* tar1 = (const float*)d_in[1];
  const float* src2 = (const float*)d_in[2];  // [4,2048,32,32]
  const float* tar2 = (const float*)d_in[3];
  float* out = (float*)d_out;                 // [4,6144,64,64] = 384 MiB

  // scratch in d_out (consumed before the final output writes):
  u8* scratch = (u8*)d_out;
  _Float16* hi1s = (_Float16*)scratch;                       // 32 MiB [4,4096,1024]
  _Float16* lo1s = (_Float16*)(scratch + (32ull << 20));     // 32 MiB
  _Float16* hi1t = (_Float16*)(scratch + (64ull << 20));     // 32 MiB
  _Float16* lo1t = (_Float16*)(scratch + (96ull << 20));     // 32 MiB
  _Float16* hi2s = (_Float16*)(scratch + (128ull << 20));    // 16 MiB [4,1024,2048]
  _Float16* lo2s = (_Float16*)(scratch + (144ull << 20));    // 16 MiB
  _Float16* hi2t = (_Float16*)(scratch + (160ull << 20));    // 16 MiB
  _Float16* lo2t = (_Float16*)(scratch + (176ull << 20));    // 16 MiB
  u8* sc1 = scratch + (192ull << 20);                        // 64 MiB u8
  u8* sc2 = scratch + (256ull << 20);                        // 4 MiB u8
  unsigned short* tmin1 = (unsigned short*)(scratch + (261ull << 20));  // 512 KiB
  unsigned short* tmin2 = (unsigned short*)(scratch + (262ull << 20));  // 32 KiB
  float* hnp1 = (float*)(scratch + (263ull << 20));          // 2 MiB [4,32,4096]
  float* hnp2 = (float*)(scratch + (266ull << 20));          // 1 MiB [4,64,1024]

  float* hn1 = (float*)d_ws;              // 4*4096 f32
  float* hn2 = hn1 + 4 * 4096;            // 4*1024 f32
  unsigned* idx1 = (unsigned*)(hn2 + 4 * 1024);  // 4*4096 u32
  unsigned* idx2 = idx1 + 4 * 4096;              // 4*1024 u32

  prep_all<<<6144, 256, 0, stream>>>(src1, tar1, src2, tar2,
                                     hi1s, lo1s, hi1t, lo1t,
                                     hi2s, lo2s, hi2t, lo2t, hnp1, hnp2);
  hn_all<<<dim3(20, 4), 256, 0, stream>>>(hnp1, hnp2, hn1, hn2);

  // merged filter: 64 L2 blocks (long poles, first) + 1024 L1 blocks
  nn_filter_all<<<1088, 512, 0, stream>>>(
      (const u8*)hi1s, (const u8*)hi1t, hn1, sc1, tmin1,
      (const u8*)hi2s, (const u8*)hi2t, hn2, sc2, tmin2);

  // merged select: 1024 L1 row-blocks + 256 L2 row-blocks
  select_all<<<dim3(1280, 4), 256, 0, stream>>>(
      sc1, tmin1, hi1s, lo1s, hi1t, lo1t, hn1, idx1,
      sc2, tmin2, hi2s, lo2s, hi2t, lo2t, hn2, idx2);

  finalize<<<dim3(6144, 4), 256, 0, stream>>>(src1, tar1, src2, tar2, idx1, idx2, out);
}

// Round 13
// 518.075 us; speedup vs baseline: 1.1453x; 1.1453x over previous
//
#include <hip/hip_runtime.h>
#include <cstdint>

using u8 = unsigned char;
using u64 = unsigned long long;

typedef _Float16 f16x8 __attribute__((ext_vector_type(8)));
typedef float f32x4 __attribute__((ext_vector_type(4)));
typedef unsigned short u16x8 __attribute__((ext_vector_type(8)));

__device__ __forceinline__ void gload16(const void* g, void* l) {
  __builtin_amdgcn_global_load_lds((const __attribute__((address_space(1))) void*)g,
                                   (__attribute__((address_space(3))) void*)l, 16, 0, 0);
}

#define VMCNT(N) asm volatile("s_waitcnt vmcnt(" #N ")" ::: "memory")

// ---- fp32 [C][N] slice -> f16 hi/lo planes [N][C]; 64-ch chunk per block so
// each thread writes a FULL 128B line per plane (no partial-line writes).
__device__ __forceinline__ void split_body(const float* __restrict__ in,
                                           _Float16* __restrict__ hi,
                                           _Float16* __restrict__ lo,
                                           float* __restrict__ hnp,
                                           int C, int N, int NC,
                                           int cblk, int nblk, int b, bool with_hn) {
  const int n = nblk * 256 + (int)threadIdx.x;
  const int c0 = cblk * 64;
  const float* inB = in + (size_t)b * C * N;
  f16x8 hv[8], lv[8];
  float ss = 0.f;
#pragma unroll
  for (int g = 0; g < 8; ++g)
#pragma unroll
    for (int e = 0; e < 8; ++e) {
      float x = inB[(size_t)(c0 + g * 8 + e) * N + n];
      _Float16 h = (_Float16)x;
      float r = (x - (float)h) * 4096.f;
      hv[g][e] = h;
      lv[g][e] = (_Float16)r;
      ss = fmaf(x, x, ss);
    }
  _Float16* oh = hi + ((size_t)b * N + n) * C + c0;
  _Float16* ol = lo + ((size_t)b * N + n) * C + c0;
#pragma unroll
  for (int g = 0; g < 8; ++g) {
    *(f16x8*)(oh + g * 8) = hv[g];
    *(f16x8*)(ol + g * 8) = lv[g];
  }
  if (with_hn) hnp[((size_t)b * NC + cblk) * N + n] = ss;
}

// one launch for all 4 tensors: 1024*2 (L1) + 512*2 (L2) = 3072 blocks
__global__ __launch_bounds__(256) void prep_all(
    const float* __restrict__ s1, const float* __restrict__ t1,
    const float* __restrict__ s2, const float* __restrict__ t2,
    _Float16* __restrict__ h1s, _Float16* __restrict__ l1s,
    _Float16* __restrict__ h1t, _Float16* __restrict__ l1t,
    _Float16* __restrict__ h2s, _Float16* __restrict__ l2s,
    _Float16* __restrict__ h2t, _Float16* __restrict__ l2t,
    float* __restrict__ hnp1, float* __restrict__ hnp2) {
  const int f = (int)blockIdx.x;
  if (f < 2048) {  // L1: C=1024 (16 cblks of 64), N=4096 (16 nblks), 4 b
    const bool isT = f >= 1024;
    const int local = f & 1023;
    const int cblk = local & 15;
    const int r = local >> 4;
    const int nblk = r & 15, b = r >> 4;
    split_body(isT ? t1 : s1, isT ? h1t : h1s, isT ? l1t : l1s, hnp1,
               1024, 4096, 16, cblk, nblk, b, isT);
  } else {         // L2: C=2048 (32 cblks of 64), N=1024 (4 nblks), 4 b
    const int l0 = f - 2048;
    const bool isT = l0 >= 512;
    const int local = l0 & 511;
    const int cblk = local & 31;
    const int r = local >> 5;
    const int nblk = r & 3, b = r >> 2;
    split_body(isT ? t2 : s2, isT ? h2t : h2s, isT ? l2t : l2s, hnp2,
               2048, 1024, 32, cblk, nblk, b, isT);
  }
}

// ---- hn[b][n] = 0.5 * sum over chunks, both levels in one launch ------------
__global__ __launch_bounds__(256) void hn_all(const float* __restrict__ hnp1,
                                              const float* __restrict__ hnp2,
                                              float* __restrict__ hn1,
                                              float* __restrict__ hn2) {
  const int x = (int)blockIdx.x, b = (int)blockIdx.y;
  if (x < 16) {
    const int n = x * 256 + (int)threadIdx.x;
    float a = 0.f;
    for (int cc = 0; cc < 16; ++cc) a += hnp1[((size_t)b * 16 + cc) * 4096 + n];
    hn1[(size_t)b * 4096 + n] = 0.5f * a;
  } else {
    const int n = (x - 16) * 256 + (int)threadIdx.x;
    float a = 0.f;
    for (int cc = 0; cc < 32; ++cc) a += hnp2[((size_t)b * 32 + cc) * 1024 + n];
    hn2[(size_t)b * 1024 + n] = 0.5f * a;
  }
}

// ---- f16-hi filter GEMM, validated phase schedule; L1+L2 in ONE launch ------
#define MFMA_BLOCK(GI)                                                         \
  __builtin_amdgcn_s_barrier();                                                \
  asm volatile("s_waitcnt lgkmcnt(0)" ::: "memory");                           \
  __builtin_amdgcn_sched_barrier(0);                                           \
  __builtin_amdgcn_s_setprio(1);                                               \
  _Pragma("unroll") for (int i2 = 0; i2 < 4; ++i2)                             \
      _Pragma("unroll") for (int j = 0; j < NJ; ++j) acc[(GI)*4 + i2][j] =     \
      __builtin_amdgcn_mfma_f32_16x16x32_f16(av[i2], bv[j],                    \
                                             acc[(GI)*4 + i2][j], 0, 0, 0);    \
  __builtin_amdgcn_s_setprio(0);                                               \
  asm volatile("" ::: "memory");                                               \
  __builtin_amdgcn_s_barrier();

// body: 256x256 tile, 512 threads (2x4 waves), MI=8, NJ=4, G=2
__device__ __forceinline__ void filter_body(
    const u8* __restrict__ Ahi, const u8* __restrict__ Bhi,
    const float* __restrict__ hn, unsigned short* __restrict__ sc,
    int M, int N, int NT, int mbase, int nbase, int b, u8* smem) {
  constexpr int MI = 8, NJ = 4;
  constexpr int BM = 256;
  constexpr int CHUNK_A = BM * 64;   // 16 KB
  constexpr int CHUNK = 2 * CHUNK_A; // 32 KB
  constexpr int NTH = 512;

  const int tid = threadIdx.x;
  const int lane = tid & 63;
  const int wid = tid >> 6;
  const int wrow = wid >> 2;   // /4
  const int wcol = wid & 3;    // %4
  const int lr = lane & 15, kh = lane >> 4;
  const size_t rstride = (size_t)NT * 128;

  const int r0 = (tid >> 6) * 16 + ((tid & 63) >> 2);
  const int sA = ((lane & 3) ^ (r0 >> 1)) & 3;
  const u8* aP0 = Ahi + ((size_t)b * M + mbase + r0) * rstride + sA * 16;
  const u8* aP1 = aP0 + (size_t)(NTH / 4) * rstride;
  const u8* bP0 = Bhi + ((size_t)b * N + nbase + r0) * rstride + sA * 16;
  const u8* bP1 = bP0 + (size_t)(NTH / 4) * rstride;

  auto STAGE = [&](int X, int h) {
    const size_t ko = (size_t)X * 128 + h * 64;
    u8* cb = smem + ((X & 1) * 2 + h) * CHUNK;
    gload16(aP0 + ko, cb + tid * 16);
    gload16(aP1 + ko, cb + NTH * 16 + tid * 16);
    gload16(bP0 + ko, cb + CHUNK_A + tid * 16);
    gload16(bP1 + ko, cb + CHUNK_A + NTH * 16 + tid * 16);
  };

  int a_off[MI], b_off[NJ];
#pragma unroll
  for (int i = 0; i < MI; ++i) {
    const int row = wrow * (MI * 16) + i * 16 + lr;
    a_off[i] = row * 64 + (((kh ^ (row >> 1)) & 3) << 4);
  }
#pragma unroll
  for (int j = 0; j < NJ; ++j) {
    const int row = wcol * (NJ * 16) + j * 16 + lr;
    b_off[j] = CHUNK_A + row * 64 + (((kh ^ (row >> 1)) & 3) << 4);
  }

  f32x4 acc[MI][NJ];
#pragma unroll
  for (int i = 0; i < MI; ++i)
#pragma unroll
    for (int j = 0; j < NJ; ++j) acc[i][j] = f32x4{0.f, 0.f, 0.f, 0.f};

  STAGE(0, 0);
  STAGE(0, 1);
  STAGE(1, 0);
  VMCNT(8);
  __builtin_amdgcn_s_barrier();

  for (int X = 0; X < NT; ++X) {
    const u8* cb0 = smem + ((X & 1) * 2) * CHUNK;
    const u8* cb1 = cb0 + CHUNK;
    f16x8 av[4], bv[NJ];

#pragma unroll
    for (int j = 0; j < NJ; ++j) bv[j] = *(const f16x8*)(cb0 + b_off[j]);
#pragma unroll
    for (int i2 = 0; i2 < 4; ++i2) av[i2] = *(const f16x8*)(cb0 + a_off[i2]);
    if (X + 1 < NT) STAGE(X + 1, 1);
    if (X + 1 < NT) { VMCNT(8); } else { VMCNT(0); }
    MFMA_BLOCK(0)

#pragma unroll
    for (int i2 = 0; i2 < 4; ++i2) av[i2] = *(const f16x8*)(cb0 + a_off[4 + i2]);
    MFMA_BLOCK(1)

#pragma unroll
    for (int j = 0; j < NJ; ++j) bv[j] = *(const f16x8*)(cb1 + b_off[j]);
#pragma unroll
    for (int i2 = 0; i2 < 4; ++i2) av[i2] = *(const f16x8*)(cb1 + a_off[i2]);
    if (X + 2 < NT) STAGE(X + 2, 0);
    if (X + 1 < NT) {
      if (X + 2 < NT) { VMCNT(8); } else { VMCNT(4); }
    }
    MFMA_BLOCK(0)

#pragma unroll
    for (int i2 = 0; i2 < 4; ++i2) av[i2] = *(const f16x8*)(cb1 + a_off[4 + i2]);
    MFMA_BLOCK(1)
  }

  // epilogue: quantized score store. C/D: col=lane&15, row=(lane>>4)*4+r
  const float* hnB = hn + (size_t)b * N;
  float hnv[NJ];
  int ncol[NJ];
#pragma unroll
  for (int j = 0; j < NJ; ++j) {
    ncol[j] = nbase + wcol * (NJ * 16) + j * 16 + lr;
    hnv[j] = hnB[ncol[j]];
  }
  unsigned short* scB = sc + (size_t)b * M * N;
#pragma unroll
  for (int i = 0; i < MI; ++i)
#pragma unroll
    for (int r = 0; r < 4; ++r) {
      const int m = mbase + wrow * (MI * 16) + i * 16 + kh * 4 + r;
      unsigned short* srow = scB + (size_t)m * N;
#pragma unroll
      for (int j = 0; j < NJ; ++j) {
        float score = hnv[j] - acc[i][j][r];
        int qi = (int)(score * 64.0f);
        qi = qi < 0 ? 0 : (qi > 65535 ? 65535 : qi);
        srow[ncol[j]] = (unsigned short)qi;
      }
    }
}

// merged launch: blocks [0,64) = L2 (M=N=1024, NT=32, long poles first),
// blocks [64, 1088) = L1 (M=N=4096, NT=16, 16x16 grid).
__global__ __launch_bounds__(512, 2) void nn_filter_all(
    const u8* __restrict__ A1, const u8* __restrict__ B1,
    const float* __restrict__ hn1, unsigned short* __restrict__ sc1,
    const u8* __restrict__ A2, const u8* __restrict__ B2,
    const float* __restrict__ hn2, unsigned short* __restrict__ sc2) {
  __shared__ u8 smem[4 * 32768];  // 128 KB
  const int bid = (int)blockIdx.x;
  if (bid < 64) {
    const int sbid = (bid & 7) * 8 + (bid >> 3);
    const int b = sbid >> 4;
    const int rr = sbid & 15;
    const int n1 = rr & 3;
    const int mb = rr >> 2;
    filter_body(A2, B2, hn2, sc2, 1024, 1024, 32, mb * 256, n1 * 256, b, smem);
  } else {
    const int l = bid - 64;
    const int sbid = (l & 7) * 128 + (l >> 3);
    const int perB = 256;  // 16 x 16
    const int b = sbid / perB;
    const int rr = sbid - b * perB;
    const int n1 = rr & 3;
    const int t2 = rr >> 2;
    const int mb = t2 & 15;
    const int n2 = t2 >> 4;
    filter_body(A1, B1, hn1, sc1, 4096, 4096, 16, mb * 256, (n2 * 4 + n1) * 256, b, smem);
  }
}

// ---- select + exact rescore: one wave per source row (round-7/11 body) ------
template <int K, int CH>
__device__ __forceinline__ void select_body(
    const unsigned short* __restrict__ sc,
    const _Float16* __restrict__ hiA, const _Float16* __restrict__ loA,
    const _Float16* __restrict__ hiB, const _Float16* __restrict__ loB,
    const float* __restrict__ hn, unsigned* __restrict__ idx,
    int M, int N, int rowblk, int b) {
  const int w = threadIdx.x >> 6, lane = threadIdx.x & 63;
  const int row = rowblk * 4 + w;
  const unsigned short* q = sc + ((size_t)b * M + row) * N;

  unsigned cm[CH];
#pragma unroll
  for (int ch = 0; ch < CH; ++ch) {
    u16x8 v = *(const u16x8*)(q + ch * 512 + lane * 8);
    unsigned m0 = v[0] < v[1] ? v[0] : v[1];
    unsigned m1 = v[2] < v[3] ? v[2] : v[3];
    unsigned m2 = v[4] < v[5] ? v[4] : v[5];
    unsigned m3 = v[6] < v[7] ? v[6] : v[7];
    m0 = m0 < m1 ? m0 : m1;
    m2 = m2 < m3 ? m2 : m3;
    unsigned m = m0 < m2 ? m0 : m2;
#pragma unroll
    for (int off = 32; off >= 1; off >>= 1) {
      unsigned o = (unsigned)__shfl_xor((int)m, off);
      m = o < m ? o : m;
    }
    cm[ch] = m;
  }
  unsigned mn = 0xFFFFu;
#pragma unroll
  for (int ch = 0; ch < CH; ++ch) mn = cm[ch] < mn ? cm[ch] : mn;
  const unsigned thr = mn + 64;

  constexpr int PER = K / 64;
  const float inv = 2.44140625e-4f;
  float sv[PER];
  const _Float16* hA = hiA + ((size_t)b * M + row) * K;
  const _Float16* lA = loA + ((size_t)b * M + row) * K;
#pragma unroll
  for (int i = 0; i < PER; ++i)
    sv[i] = fmaf((float)lA[i * 64 + lane], inv, (float)hA[i * 64 + lane]);

  float bestv = 3.4e38f;
  int bestn = 0x7FFFFFFF;
  const float* hnB = hn + (size_t)b * N;
#pragma unroll
  for (int ch = 0; ch < CH; ++ch) {
    if (cm[ch] > thr) continue;
    u16x8 v = *(const u16x8*)(q + ch * 512 + lane * 8);
#pragma unroll
    for (int e = 0; e < 8; ++e) {
      u64 mask = __ballot((unsigned)v[e] <= thr);
      while (mask) {
        int bit = __ffsll((long long)mask) - 1;
        mask &= mask - 1;
        int n = ch * 512 + bit * 8 + e;
        const _Float16* hB = hiB + ((size_t)b * N + n) * K;
        const _Float16* lB = loB + ((size_t)b * N + n) * K;
        float part = 0.f;
#pragma unroll
        for (int i = 0; i < PER; ++i)
          part = fmaf(sv[i], fmaf((float)lB[i * 64 + lane], inv, (float)hB[i * 64 + lane]), part);
#pragma unroll
        for (int off = 32; off >= 1; off >>= 1) part += __shfl_xor(part, off);
        float scf = hnB[n] - part;
        if (scf < bestv || (scf == bestv && n < bestn)) { bestv = scf; bestn = n; }
      }
    }
  }
  if (lane == 0) idx[(size_t)b * M + row] = (unsigned)bestn;
}

__global__ __launch_bounds__(256) void select_all(
    const unsigned short* __restrict__ sc1,
    const _Float16* __restrict__ h1s, const _Float16* __restrict__ l1s,
    const _Float16* __restrict__ h1t, const _Float16* __restrict__ l1t,
    const float* __restrict__ hn1, unsigned* __restrict__ idx1,
    const unsigned short* __restrict__ sc2,
    const _Float16* __restrict__ h2s, const _Float16* __restrict__ l2s,
    const _Float16* __restrict__ h2t, const _Float16* __restrict__ l2t,
    const float* __restrict__ hn2, unsigned* __restrict__ idx2) {
  const int x = (int)blockIdx.x, b = (int)blockIdx.y;
  if (x < 1024)
    select_body<1024, 8>(sc1, h1s, l1s, h1t, l1t, hn1, idx1, 4096, 4096, x, b);
  else
    select_body<2048, 2>(sc2, h2s, l2s, h2t, l2t, hn2, idx2, 1024, 1024, x - 1024, b);
}

// ---- finalize: c1 = [src1|gather] and upsampled c2, one launch --------------
__global__ __launch_bounds__(256) void finalize(
    const float* __restrict__ src1, const float* __restrict__ tar1,
    const float* __restrict__ src2, const float* __restrict__ tar2,
    const unsigned* __restrict__ idx1, const unsigned* __restrict__ idx2,
    float* __restrict__ out) {
  const int b = blockIdx.y;
  int c = (int)blockIdx.x;
  if (c < 2048) {
    float* orow = out + ((size_t)b * 6144 + c) * 4096;
    if (c < 1024) {
      const float4* s4 = (const float4*)(src1 + ((size_t)b * 1024 + c) * 4096);
      float4* o4 = (float4*)orow;
#pragma unroll
      for (int i = 0; i < 4; ++i) o4[threadIdx.x + i * 256] = s4[threadIdx.x + i * 256];
    } else {
      const float* trow = tar1 + ((size_t)b * 1024 + (c - 1024)) * 4096;
      const unsigned* ib = idx1 + (size_t)b * 4096;
      for (int p = threadIdx.x; p < 4096; p += 256) orow[p] = trow[ib[p]];
    }
    return;
  }
  c -= 2048;  // upsample channel 0..4095
  __shared__ float row[1024];
  if (c < 2048) {
    const float* in = src2 + ((size_t)b * 2048 + c) * 1024;
    for (int p = threadIdx.x; p < 1024; p += 256) row[p] = in[p];
  } else {
    const float* trow = tar2 + ((size_t)b * 2048 + (c - 2048)) * 1024;
    const unsigned* ib = idx2 + (size_t)b * 1024;
    for (int p = threadIdx.x; p < 1024; p += 256) row[p] = trow[ib[p]];
  }
  __syncthreads();
  float* orow = out + ((size_t)b * 6144 + 2048 + c) * 4096;
  for (int q = threadIdx.x; q < 4096; q += 256) {
    int y = q >> 6, x = q & 63;
    int ky = y >> 1, kx = x >> 1;
    int y0, y1, x0, x1;
    float wy0, wy1, wx0, wx1;
    if (y & 1) { y0 = ky; y1 = (ky + 1 < 32) ? ky + 1 : 31; wy0 = 0.75f; wy1 = 0.25f; }
    else       { y0 = (ky > 0) ? ky - 1 : 0; y1 = ky;       wy0 = 0.25f; wy1 = 0.75f; }
    if (x & 1) { x0 = kx; x1 = (kx + 1 < 32) ? kx + 1 : 31; wx0 = 0.75f; wx1 = 0.25f; }
    else       { x0 = (kx > 0) ? kx - 1 : 0; x1 = kx;       wx0 = 0.25f; wx1 = 0.75f; }
    float v = wy0 * (wx0 * row[y0 * 32 + x0] + wx1 * row[y0 * 32 + x1]) +
              wy1 * (wx0 * row[y1 * 32 + x0] + wx1 * row[y1 * 32 + x1]);
    orow[q] = v;
  }
}

// ---------------- launch -----------------------------------------------------
extern "C" void kernel_launch(void* const* d_in, const int* in_sizes, int n_in,
                              void* d_out, int out_size, void* d_ws, size_t ws_size,
                              hipStream_t stream) {
  const float* src1 = (const float*)d_in[0];  // [4,1024,64,64]
  const float* tar1 = (const float*)d_in[1];
  const float* src2 = (const float*)d_in[2];  // [4,2048,32,32]
  const float* tar2 = (const float*)d_in[3];
  float* out = (float*)d_out;                 // [4,6144,64,64] = 384 MiB

  // scratch in d_out (consumed before the final output writes):
  u8* scratch = (u8*)d_out;
  _Float16* hi1s = (_Float16*)scratch;                       // 32 MiB [4,4096,1024]
  _Float16* lo1s = (_Float16*)(scratch + (32ull << 20));     // 32 MiB
  _Float16* hi1t = (_Float16*)(scratch + (64ull << 20));     // 32 MiB
  _Float16* lo1t = (_Float16*)(scratch + (96ull << 20));     // 32 MiB
  _Float16* hi2s = (_Float16*)(scratch + (128ull << 20));    // 16 MiB [4,1024,2048]
  _Float16* lo2s = (_Float16*)(scratch + (144ull << 20));    // 16 MiB
  _Float16* hi2t = (_Float16*)(scratch + (160ull << 20));    // 16 MiB
  _Float16* lo2t = (_Float16*)(scratch + (176ull << 20));    // 16 MiB
  unsigned short* sc1 = (unsigned short*)(scratch + (192ull << 20));  // 128 MiB
  unsigned short* sc2 = (unsigned short*)(scratch + (320ull << 20));  // 8 MiB
  float* hnp1 = (float*)(scratch + (328ull << 20));          // 1 MiB [4,16,4096]
  float* hnp2 = (float*)(scratch + (330ull << 20));          // 0.5 MiB [4,32,1024]

  float* hn1 = (float*)d_ws;              // 4*4096 f32
  float* hn2 = hn1 + 4 * 4096;            // 4*1024 f32
  unsigned* idx1 = (unsigned*)(hn2 + 4 * 1024);  // 4*4096 u32
  unsigned* idx2 = idx1 + 4 * 4096;              // 4*1024 u32

  prep_all<<<3072, 256, 0, stream>>>(src1, tar1, src2, tar2,
                                     hi1s, lo1s, hi1t, lo1t,
                                     hi2s, lo2s, hi2t, lo2t, hnp1, hnp2);
  hn_all<<<dim3(20, 4), 256, 0, stream>>>(hnp1, hnp2, hn1, hn2);

  // merged filter: 64 L2 blocks (long poles, first) + 1024 L1 blocks
  nn_filter_all<<<1088, 512, 0, stream>>>(
      (const u8*)hi1s, (const u8*)hi1t, hn1, sc1,
      (const u8*)hi2s, (const u8*)hi2t, hn2, sc2);

  // merged select: 1024 L1 row-blocks + 256 L2 row-blocks
  select_all<<<dim3(1280, 4), 256, 0, stream>>>(
      sc1, hi1s, lo1s, hi1t, lo1t, hn1, idx1,
      sc2, hi2s, lo2s, hi2t, lo2t, hn2, idx2);

  finalize<<<dim3(6144, 4), 256, 0, stream>>>(src1, tar1, src2, tar2, idx1, idx2, out);
}